// Round 2
// baseline (405.113 us; speedup 1.0000x reference)
//
#include <hip/hip_runtime.h>
#include <hip/hip_bf16.h>
#include <cstdint>
#include <cstddef>

// ---------------------------------------------------------------------------
// SeparableCritic: out = l2norm(MLP(x)) @ l2norm(MLP(y))^T
// N=8192, D=64, H=512, L=128. Inputs/outputs fp32; internal compute bf16 MFMA
// (threshold has bf16 floor_eps_k=8, so bf16 internals are permitted).
// Round 2: fp32 I/O + device-side bf16 cast, batched x/y encoder, fp32 z/l2norm.
// ---------------------------------------------------------------------------

typedef unsigned short u16;
typedef __attribute__((ext_vector_type(8))) short bf16x8;  // 8 bf16 = 4 VGPRs
typedef __attribute__((ext_vector_type(4))) float f32x4;   // MFMA C/D

__device__ __forceinline__ u16 f_to_bf16_bits(float f) {
    union { float f; uint32_t u; } v; v.f = f;
    uint32_t lsb = (v.u >> 16) & 1u;
    return (u16)((v.u + 0x7fffu + lsb) >> 16);   // round-to-nearest-even
}

// fp32 -> bf16 elementwise cast.
__global__ __launch_bounds__(256) void cast_f32_bf16_kernel(
    const float* __restrict__ in, u16* __restrict__ out, int n)
{
    int i = blockIdx.x * 256 + threadIdx.x;
    if (i < n) out[i] = f_to_bf16_bits(in[i]);
}

// in[R][C] fp32 -> out[C][R] bf16 (weight transpose+cast; tiny, L2-served).
__global__ __launch_bounds__(256) void transpose_cast_kernel(
    const float* __restrict__ in, u16* __restrict__ out, int R, int C)
{
    int idx = blockIdx.x * 256 + threadIdx.x;
    if (idx < R * C) {
        int r = idx / C, c = idx - r * C;
        out[c * R + r] = f_to_bf16_bits(in[r * C + c]);
    }
}

// C[M,N] = act(A[M,K] @ BT[N,K]^T + bias). A,BT row-major bf16.
// bias fp32 (or null). Output bf16 (Cb) or fp32 (Cf) per OUT_F32.
// Block: 256 thr = 4 waves in 2x2, each wave 64x64 (4x4 tiles of 16x16x32).
// M,N multiples of 128; K multiple of 32.
template<bool RELU, bool BIAS, bool OUT_F32>
__global__ __launch_bounds__(256) void gemm_bt_kernel(
    const u16* __restrict__ A, const u16* __restrict__ BT,
    const float* __restrict__ bias,
    u16* __restrict__ Cb, float* __restrict__ Cf,
    int M, int N, int K)
{
    const int lane = threadIdx.x & 63;
    const int wave = threadIdx.x >> 6;
    const int wm = wave >> 1, wn = wave & 1;
    const int m_base = blockIdx.y * 128 + wm * 64;
    const int n_base = blockIdx.x * 128 + wn * 64;
    const int mi   = lane & 15;   // A row / B col / C col within 16-tile
    const int quad = lane >> 4;   // k-subrange selector; C row group

    f32x4 acc[4][4];
    #pragma unroll
    for (int i = 0; i < 4; ++i)
        #pragma unroll
        for (int j = 0; j < 4; ++j)
            acc[i][j] = f32x4{0.f, 0.f, 0.f, 0.f};

    // A-frag: A[m=16t+mi][k=quad*8+j]; B-frag: BT[n=16t+mi][k=quad*8+j].
    const u16* arow[4];
    const u16* brow[4];
    #pragma unroll
    for (int i = 0; i < 4; ++i)
        arow[i] = A + (size_t)(m_base + i * 16 + mi) * K + quad * 8;
    #pragma unroll
    for (int j = 0; j < 4; ++j)
        brow[j] = BT + (size_t)(n_base + j * 16 + mi) * K + quad * 8;

    for (int k0 = 0; k0 < K; k0 += 32) {
        bf16x8 af[4], bfr[4];
        #pragma unroll
        for (int i = 0; i < 4; ++i)
            af[i] = *reinterpret_cast<const bf16x8*>(arow[i] + k0);
        #pragma unroll
        for (int j = 0; j < 4; ++j)
            bfr[j] = *reinterpret_cast<const bf16x8*>(brow[j] + k0);
        #pragma unroll
        for (int i = 0; i < 4; ++i)
            #pragma unroll
            for (int j = 0; j < 4; ++j)
                acc[i][j] = __builtin_amdgcn_mfma_f32_16x16x32_bf16(
                    af[i], bfr[j], acc[i][j], 0, 0, 0);
    }

    // Epilogue: C/D layout col = lane&15, row = quad*4 + reg [m89-verified].
    #pragma unroll
    for (int j = 0; j < 4; ++j) {
        const int col = n_base + j * 16 + mi;
        float bv = BIAS ? bias[col] : 0.f;
        #pragma unroll
        for (int i = 0; i < 4; ++i) {
            const int row0 = m_base + i * 16 + quad * 4;
            #pragma unroll
            for (int r = 0; r < 4; ++r) {
                float v = acc[i][j][r] + bv;
                if (RELU) v = fmaxf(v, 0.f);
                if (OUT_F32) Cf[(size_t)(row0 + r) * N + col] = v;
                else         Cb[(size_t)(row0 + r) * N + col] = f_to_bf16_bits(v);
            }
        }
    }
}

// One wave per row of z[rows][128] fp32: lane holds 2 floats, butterfly-
// reduce sumsq, scale by 1/max(||z||, eps), write bf16 packed pair.
__global__ __launch_bounds__(256) void l2norm_kernel(
    const float* __restrict__ z, u16* __restrict__ zn)
{
    const int row  = blockIdx.x * 4 + (threadIdx.x >> 6);
    const int lane = threadIdx.x & 63;
    const float2* zp = reinterpret_cast<const float2*>(z + (size_t)row * 128);
    float2 p = zp[lane];
    float s = p.x * p.x + p.y * p.y;
    #pragma unroll
    for (int off = 32; off > 0; off >>= 1)
        s += __shfl_xor(s, off, 64);
    float inv = 1.0f / fmaxf(sqrtf(s), 1e-12f);
    uint32_t outp = (uint32_t)f_to_bf16_bits(p.x * inv)
                  | ((uint32_t)f_to_bf16_bits(p.y * inv) << 16);
    reinterpret_cast<uint32_t*>(zn + (size_t)row * 128)[lane] = outp;
}

extern "C" void kernel_launch(void* const* d_in, const int* in_sizes, int n_in,
                              void* d_out, int out_size, void* d_ws, size_t ws_size,
                              hipStream_t stream)
{
    const float* x  = (const float*)d_in[0];   // [8192, 64]
    const float* y  = (const float*)d_in[1];   // [8192, 64]
    const float* W1 = (const float*)d_in[2];   // [64, 512]
    const float* b1 = (const float*)d_in[3];   // [512]
    const float* W2 = (const float*)d_in[4];   // [512, 512]
    const float* b2 = (const float*)d_in[5];   // [512]
    const float* W3 = (const float*)d_in[6];   // [512, 128]
    const float* b3 = (const float*)d_in[7];   // [128]
    float* out = (float*)d_out;                // [8192, 8192] fp32

    // Workspace layout. bf16 regions as u16, z as fp32. Total ~47 MB.
    u16* ws  = (u16*)d_ws;
    u16* xy  = ws;                              // [16384][64] bf16
    u16* W1T = xy  + (size_t)16384 * 64;        // [512][64]
    u16* W2T = W1T + 512 * 64;                  // [512][512]
    u16* W3T = W2T + 512 * 512;                 // [128][512]
    u16* h1  = W3T + 128 * 512;                 // [16384][512] bf16
    u16* h2  = h1  + (size_t)16384 * 512;       // [16384][512] bf16
    u16* zn  = h2  + (size_t)16384 * 512;       // [16384][128] bf16
    float* z = (float*)(zn + (size_t)16384 * 128); // [16384][128] fp32 (8B-aligned: offset even)

    dim3 blk(256);

    // Cast inputs -> bf16 (x into rows 0..8191, y into rows 8192..16383).
    cast_f32_bf16_kernel<<<(8192 * 64 + 255) / 256, blk, 0, stream>>>(
        x, xy, 8192 * 64);
    cast_f32_bf16_kernel<<<(8192 * 64 + 255) / 256, blk, 0, stream>>>(
        y, xy + (size_t)8192 * 64, 8192 * 64);

    // Transpose+cast weights to [N][K] bf16 so B-fragments are contiguous.
    transpose_cast_kernel<<<(64 * 512 + 255) / 256, blk, 0, stream>>>(W1, W1T, 64, 512);
    transpose_cast_kernel<<<(512 * 512 + 255) / 256, blk, 0, stream>>>(W2, W2T, 512, 512);
    transpose_cast_kernel<<<(512 * 128 + 255) / 256, blk, 0, stream>>>(W3, W3T, 512, 128);

    // Encoder (shared weights for x and y, per reference), batched M=16384.
    gemm_bt_kernel<true, true, false><<<dim3(4, 128), blk, 0, stream>>>(
        xy, W1T, b1, h1, nullptr, 16384, 512, 64);
    gemm_bt_kernel<true, true, false><<<dim3(4, 128), blk, 0, stream>>>(
        h1, W2T, b2, h2, nullptr, 16384, 512, 512);
    gemm_bt_kernel<false, true, true><<<dim3(1, 128), blk, 0, stream>>>(
        h2, W3T, b3, nullptr, z, 16384, 128, 512);

    // L2 normalize fp32 -> bf16 (zx rows 0..8191, zy rows 8192..16383).
    l2norm_kernel<<<16384 / 4, blk, 0, stream>>>(z, zn);

    // out = zx @ zy^T, fp32 output (TEMP=1.0).
    gemm_bt_kernel<false, false, true><<<dim3(64, 64), blk, 0, stream>>>(
        zn, zn + (size_t)8192 * 128, nullptr, nullptr, out, 8192, 8192, 128);
}

// Round 3
// 378.455 us; speedup vs baseline: 1.0704x; 1.0704x over previous
//
#include <hip/hip_runtime.h>
#include <hip/hip_bf16.h>
#include <cstdint>
#include <cstddef>

// ---------------------------------------------------------------------------
// SeparableCritic: out = l2norm(MLP(x)) @ l2norm(MLP(y))^T
// N=8192, D=64, H=512, L=128. fp32 I/O, bf16 MFMA internals.
// Round 3: m97-style GEMM — global_load_lds(16B) staging into fragment-ordered
// LDS (conflict-free ds_read_b128 at lane*16), 128x128 tile, 4 waves.
// ---------------------------------------------------------------------------

typedef unsigned short u16;
typedef __attribute__((ext_vector_type(8))) short bf16x8;  // 8 bf16 = 4 VGPRs
typedef __attribute__((ext_vector_type(4))) float f32x4;   // MFMA C/D

__device__ __forceinline__ u16 f_to_bf16_bits(float f) {
    union { float f; uint32_t u; } v; v.f = f;
    uint32_t lsb = (v.u >> 16) & 1u;
    return (u16)((v.u + 0x7fffu + lsb) >> 16);   // round-to-nearest-even
}

// fp32 -> bf16 elementwise cast.
__global__ __launch_bounds__(256) void cast_f32_bf16_kernel(
    const float* __restrict__ in, u16* __restrict__ out, int n)
{
    int i = blockIdx.x * 256 + threadIdx.x;
    if (i < n) out[i] = f_to_bf16_bits(in[i]);
}

// in[R][C] fp32 -> out[C][R] bf16 (weight transpose+cast; tiny, L2-served).
__global__ __launch_bounds__(256) void transpose_cast_kernel(
    const float* __restrict__ in, u16* __restrict__ out, int R, int C)
{
    int idx = blockIdx.x * 256 + threadIdx.x;
    if (idx < R * C) {
        int r = idx / C, c = idx - r * C;
        out[c * R + r] = f_to_bf16_bits(in[r * C + c]);
    }
}

// C[M,N] = act(A[M,K] @ BT[N,K]^T + bias). A,BT row-major bf16.
// Block: 256 thr = 4 waves (2x2), 128x128 tile, each wave 64x64 (4x4 MFMA tiles).
// K-step 32. LDS: 16 fragment-blocks of 1KB, in exact MFMA lane order:
//   block t (t<8: A row-block t; t>=8: B row-block t-8), lane L holds
//   row (base + t*16 + (L&15)), k = k0 + (L>>4)*8 .. +8  at LDS byte t*1024+L*16.
// global_load_lds writes wave-uniform base + lane*16 -> layout matches by
// construction; ds_read_b128 at lane*16 is bank-conflict-free.
// M,N multiples of 128; K multiple of 32.
template<bool RELU, bool BIAS, bool OUT_F32>
__global__ __launch_bounds__(256) void gemm_lds_kernel(
    const u16* __restrict__ A, const u16* __restrict__ BT,
    const float* __restrict__ bias,
    u16* __restrict__ Cb, float* __restrict__ Cf,
    int M, int N, int K)
{
    __shared__ u16 lds[16 * 512];   // 16 KB
    const int lane = threadIdx.x & 63;
    const int wave = threadIdx.x >> 6;
    const int wm = wave >> 1, wn = wave & 1;
    const int m_base = blockIdx.y * 128;
    const int n_base = blockIdx.x * 128;
    const int mi   = lane & 15;   // frag row / C col within 16-tile
    const int quad = lane >> 4;   // frag k-subrange; C row group

    f32x4 acc[4][4];
    #pragma unroll
    for (int i = 0; i < 4; ++i)
        #pragma unroll
        for (int j = 0; j < 4; ++j)
            acc[i][j] = f32x4{0.f, 0.f, 0.f, 0.f};

    // Per-lane global source base for each of this wave's 4 stage loads.
    // Load s stages fragment-block t = wave*4 + s.
    const u16* src[4];
    #pragma unroll
    for (int s = 0; s < 4; ++s) {
        const int t = wave * 4 + s;
        if (t < 8)
            src[s] = A + (size_t)(m_base + t * 16 + mi) * K + quad * 8;
        else
            src[s] = BT + (size_t)(n_base + (t - 8) * 16 + mi) * K + quad * 8;
    }
    u16* dst_base = &lds[wave * 4 * 512];   // wave-uniform

    for (int k0 = 0; k0 < K; k0 += 32) {
        #pragma unroll
        for (int s = 0; s < 4; ++s) {
            __builtin_amdgcn_global_load_lds(
                (const __attribute__((address_space(1))) void*)(src[s] + k0),
                (__attribute__((address_space(3))) void*)(dst_base + s * 512),
                16, 0, 0);
        }
        __syncthreads();

        bf16x8 af[4], bfr[4];
        #pragma unroll
        for (int i = 0; i < 4; ++i)
            af[i] = *reinterpret_cast<const bf16x8*>(&lds[(wm * 4 + i) * 512 + lane * 8]);
        #pragma unroll
        for (int j = 0; j < 4; ++j)
            bfr[j] = *reinterpret_cast<const bf16x8*>(&lds[(8 + wn * 4 + j) * 512 + lane * 8]);

        #pragma unroll
        for (int i = 0; i < 4; ++i)
            #pragma unroll
            for (int j = 0; j < 4; ++j)
                acc[i][j] = __builtin_amdgcn_mfma_f32_16x16x32_bf16(
                    af[i], bfr[j], acc[i][j], 0, 0, 0);

        __syncthreads();
    }

    // Epilogue: C/D layout col = lane&15, row = quad*4 + reg [m89-verified].
    const int wm_base = m_base + wm * 64;
    const int wn_base = n_base + wn * 64;
    #pragma unroll
    for (int j = 0; j < 4; ++j) {
        const int col = wn_base + j * 16 + mi;
        float bv = BIAS ? bias[col] : 0.f;
        #pragma unroll
        for (int i = 0; i < 4; ++i) {
            const int row0 = wm_base + i * 16 + quad * 4;
            #pragma unroll
            for (int r = 0; r < 4; ++r) {
                float v = acc[i][j][r] + bv;
                if (RELU) v = fmaxf(v, 0.f);
                if (OUT_F32) Cf[(size_t)(row0 + r) * N + col] = v;
                else         Cb[(size_t)(row0 + r) * N + col] = f_to_bf16_bits(v);
            }
        }
    }
}

// One wave per row of z[rows][128] fp32: butterfly-reduce sumsq, scale,
// write bf16 packed pair.
__global__ __launch_bounds__(256) void l2norm_kernel(
    const float* __restrict__ z, u16* __restrict__ zn)
{
    const int row  = blockIdx.x * 4 + (threadIdx.x >> 6);
    const int lane = threadIdx.x & 63;
    const float2* zp = reinterpret_cast<const float2*>(z + (size_t)row * 128);
    float2 p = zp[lane];
    float s = p.x * p.x + p.y * p.y;
    #pragma unroll
    for (int off = 32; off > 0; off >>= 1)
        s += __shfl_xor(s, off, 64);
    float inv = 1.0f / fmaxf(sqrtf(s), 1e-12f);
    uint32_t outp = (uint32_t)f_to_bf16_bits(p.x * inv)
                  | ((uint32_t)f_to_bf16_bits(p.y * inv) << 16);
    reinterpret_cast<uint32_t*>(zn + (size_t)row * 128)[lane] = outp;
}

extern "C" void kernel_launch(void* const* d_in, const int* in_sizes, int n_in,
                              void* d_out, int out_size, void* d_ws, size_t ws_size,
                              hipStream_t stream)
{
    const float* x  = (const float*)d_in[0];   // [8192, 64]
    const float* y  = (const float*)d_in[1];   // [8192, 64]
    const float* W1 = (const float*)d_in[2];   // [64, 512]
    const float* b1 = (const float*)d_in[3];   // [512]
    const float* W2 = (const float*)d_in[4];   // [512, 512]
    const float* b2 = (const float*)d_in[5];   // [512]
    const float* W3 = (const float*)d_in[6];   // [512, 128]
    const float* b3 = (const float*)d_in[7];   // [128]
    float* out = (float*)d_out;                // [8192, 8192] fp32

    // Workspace layout. bf16 regions as u16, z fp32. Total ~47 MB.
    u16* ws  = (u16*)d_ws;
    u16* xy  = ws;                              // [16384][64] bf16
    u16* W1T = xy  + (size_t)16384 * 64;        // [512][64]
    u16* W2T = W1T + 512 * 64;                  // [512][512]
    u16* W3T = W2T + 512 * 512;                 // [128][512]
    u16* h1  = W3T + 128 * 512;                 // [16384][512] bf16
    u16* h2  = h1  + (size_t)16384 * 512;       // [16384][512] bf16
    u16* zn  = h2  + (size_t)16384 * 512;       // [16384][128] bf16
    float* z = (float*)(zn + (size_t)16384 * 128); // [16384][128] fp32

    dim3 blk(256);

    // Cast inputs -> bf16 (x rows 0..8191, y rows 8192..16383).
    cast_f32_bf16_kernel<<<(8192 * 64 + 255) / 256, blk, 0, stream>>>(
        x, xy, 8192 * 64);
    cast_f32_bf16_kernel<<<(8192 * 64 + 255) / 256, blk, 0, stream>>>(
        y, xy + (size_t)8192 * 64, 8192 * 64);

    // Transpose+cast weights to [N][K] bf16.
    transpose_cast_kernel<<<(64 * 512 + 255) / 256, blk, 0, stream>>>(W1, W1T, 64, 512);
    transpose_cast_kernel<<<(512 * 512 + 255) / 256, blk, 0, stream>>>(W2, W2T, 512, 512);
    transpose_cast_kernel<<<(512 * 128 + 255) / 256, blk, 0, stream>>>(W3, W3T, 512, 128);

    // Encoder (shared weights for x and y), batched M=16384.
    gemm_lds_kernel<true, true, false><<<dim3(4, 128), blk, 0, stream>>>(
        xy, W1T, b1, h1, nullptr, 16384, 512, 64);
    gemm_lds_kernel<true, true, false><<<dim3(4, 128), blk, 0, stream>>>(
        h1, W2T, b2, h2, nullptr, 16384, 512, 512);
    gemm_lds_kernel<false, true, true><<<dim3(1, 128), blk, 0, stream>>>(
        h2, W3T, b3, nullptr, z, 16384, 128, 512);

    // L2 normalize fp32 -> bf16 (zx rows 0..8191, zy rows 8192..16383).
    l2norm_kernel<<<16384 / 4, blk, 0, stream>>>(z, zn);

    // out = zx @ zy^T, fp32 output (TEMP=1.0).
    gemm_lds_kernel<false, false, true><<<dim3(64, 64), blk, 0, stream>>>(
        zn, zn + (size_t)8192 * 128, nullptr, nullptr, out, 8192, 8192, 128);
}